// Round 11
// baseline (317.374 us; speedup 1.0000x reference)
//
#include <hip/hip_runtime.h>
#include <math.h>

#define NT 88200        // T
#define NB 8            // batch
#define TC 1378         // T // 64

static constexpr float IN_GAIN_F = 1.8197008586099834f; // 10^(5.2/20)

// ---- workspace layout (float offsets) ----
#define OFF_A0    3072         // L0 MFMA A-pack bf16 (2048 shorts)
#define OFF_A4    4096         // L4 MFMA A-pack bf16 (3072 shorts)
#define OFF_ABF   5632         // MFMA A-frag packs (32x32x16 layout), 3 layers x 12288 shorts
#define OFF_BANDS 24064        // [B][3][C][T] = 4233600
#define OFF_XRMS  4257664      // [24][TC] — sum of squares (zeroed by k_prep, atomically acc by k_firm)
#define OFF_ENV   4290736      // [24][TC]
#define OFF_WHL   4290736      // bf16 hi/lo shifted tap tables (9216 shorts) — overlaps ENV:
                               //   written by k_prep, read by k_firm, dead before k_scan writes ENV
// end 4323808 floats ~= 17.3 MB

typedef __attribute__((ext_vector_type(8))) short short8v;
typedef __attribute__((ext_vector_type(4))) short short4v;
typedef __attribute__((ext_vector_type(4))) float float4v;
typedef __attribute__((ext_vector_type(16))) float float16v;

// sigmoid-gelu: x*sigmoid(1.702x); |err| <= 0.021, reaches output only via res (~0.01 scale)
__device__ __forceinline__ float gelus(float x) {
  float e = __builtin_amdgcn_exp2f(-2.4554670f * x);
  return x * __builtin_amdgcn_rcpf(1.f + e);
}
__device__ __forceinline__ short f2bf(float x) {        // RNE
  unsigned int u = __float_as_uint(x);
  u += 0x7fffu + ((u >> 16) & 1u);
  return (short)(u >> 16);
}
__device__ __forceinline__ short f2bft(float x) {       // truncate
  return (short)(__float_as_uint(x) >> 16);
}
__device__ __forceinline__ float bf2f(short s) {
  return __uint_as_float(((unsigned int)(unsigned short)s) << 16);
}

// ---------------------------------------------------------------- prep
// task 0: composite FIR taps -> bf16 hi/lo shifted tables (WHL) incl. zero edges;
// task 1: L0 A-pack; task 2: L4 A-pack; tasks 3..5: 32x32x16 A-packs w1..w3;
// task 6: zero XRMS accumulator.
__global__ __launch_bounds__(256) void k_prep(
    const float* __restrict__ irLL, const float* __restrict__ irLH,
    const float* __restrict__ irHL, const float* __restrict__ irHH,
    const float* __restrict__ w0, const float* __restrict__ w1,
    const float* __restrict__ w2, const float* __restrict__ w3,
    const float* __restrict__ w4, float* __restrict__ ws)
{
  int gid = blockIdx.x * 256 + threadIdx.x;
  int task = blockIdx.y;
  if (task == 0) {
    short* whl = (short*)(ws + OFF_WHL);
    if (gid < 3072) {                       // live taps
      int band = gid >> 10, j = gid & 1023;
      float v = 0.f;
      if (j < 1023) {
        if (band == 2) {                    // low: 512-tap, right-aligned
          v = (j >= 511) ? irLL[j - 511] : 0.f;
        } else {                            // high/mid: conv(irLH, irH?)
          const float* wb = (band == 0) ? irHH : irHL;
          int lo = j - 511; if (lo < 0) lo = 0;
          int hi = (j < 511) ? j : 511;
          float acc = 0.f;
          for (int i = lo; i <= hi; ++i) acc += irLH[i] * wb[j - i];
          v = acc;
        }
      }
      int entry = band * 1152 + 64 + j;
      short h = f2bf(v);
      whl[entry] = h;
      whl[entry + 4608] = f2bf(v - bf2f(h));
    } else if (gid < 4608) {                // zero edges + band 3
      int z = gid - 3072;
      int entry;
      if (z < 384) {
        int band = z >> 7, r = z & 127;
        entry = band * 1152 + (r < 64 ? r : 1024 + r);
      } else {
        entry = 3 * 1152 + (z - 384);
      }
      whl[entry] = 0;
      whl[entry + 4608] = 0;
    }
  } else if (task == 1) {                   // L0 A-pack: m=oc(16/group), K=k*2+ic (6 live)
    if (gid >= 2048) return;
    int wq = gid >> 9;
    int lane = (gid >> 3) & 63;
    int j = gid & 7;
    int l16 = lane & 15, q = lane >> 4;
    int m = wq * 16 + l16;
    int K = q * 8 + j;
    float val = (K < 6) ? w0[(m * 2 + (K & 1)) * 3 + (K >> 1)] : 0.f;
    ((short*)(ws + OFF_A0))[gid] = f2bf(val);
  } else if (task == 2) {                   // L4 A-pack: rows m=ch (2 live of 16)
    if (gid >= 3072) return;
    int s = gid >> 9;
    int lane = (gid - s * 512) >> 3;
    int j = gid & 7;
    int m = lane & 15, q = lane >> 4;
    int K = s * 32 + q * 8 + j;
    int k = K >> 6, ic = K & 63;
    float val = (m < 2) ? w4[(m * 64 + ic) * 3 + k] : 0.f;
    ((short*)(ws + OFF_A4))[gid] = f2bf(val);
  } else if (task == 6) {                   // zero XRMS (24*TC = 33072 floats)
    for (int r = 0; r < 3; ++r) {
      int i = gid * 3 + r;
      if (i < 24 * TC) ws[OFF_XRMS + i] = 0.f;
    }
  } else {                                  // 32x32x16 A-pack layer l (w1..w3)
    int l = task - 3;
    if (gid >= 12288) return;
    const float* wl = (l == 0) ? w1 : (l == 1) ? w2 : w3;
    int ocg = gid / 6144;
    int rem = gid - ocg * 6144;
    int s = rem / 512;
    int rem2 = rem - s * 512;
    int lane = rem2 >> 3;
    int j = gid & 7;
    int m = ocg * 32 + (lane & 31);
    int k = s * 16 + ((lane >> 5) << 3) + j;
    int tap = k >> 6, ic = k & 63;
    short* ap = (short*)(ws + OFF_ABF);
    ap[l * 12288 + gid] = f2bf(wl[(m * 64 + ic) * 3 + tap]);
  }
}

// ---------------------------------------------------------------- MFMA band FIR (+fused RMS partial)
// Channel-paired: one block = one batch b, BOTH channels. A-frags read once per
// wave, feed two B-streams (4 MFMAs per A-pair). 2-chain hi/lo split per ch.
// Band-3 weight table dropped from LDS: row-15 lanes alias band2/u=4 (finite
// garbage in row 15 only — discarded by m<15 guard).
#define FT 320
__global__ __launch_bounds__(256) void k_firm(const float* __restrict__ audio,
                                              float* __restrict__ ws)
{
  __shared__ short xh[2][4][1344];
  __shared__ __align__(16) short wt[6912];     // hi[3][1152] then lo[3][1152]
  __shared__ float ssum[3][5];
  int b = blockIdx.x, tile = blockIdx.y;
  int t0b = tile * FT;
  int tid = threadIdx.x;
  if (tid < 15) ssum[tid / 5][tid % 5] = 0.f;
  const short* whl = (const short*)(ws + OFF_WHL);
  {
    const uint4* srcH = (const uint4*)whl;          // hi bands 0..2: 432 uint4
    const uint4* srcL = (const uint4*)(whl + 4608); // lo bands 0..2: 432 uint4
    uint4* dst = (uint4*)wt;
    for (int i = tid; i < 432; i += 256) { dst[i] = srcH[i]; dst[432 + i] = srcL[i]; }
  }
  for (int i = tid; i < 1343; i += 256) {      // unique samples, convert once
    int g = t0b - 1022 + i;
#pragma unroll
    for (int ch = 0; ch < 2; ++ch) {
      float v = (g >= 0 && g < NT) ? audio[(b * 2 + ch) * NT + g] * IN_GAIN_F : 0.f;
      short h = f2bf(v);
#pragma unroll
      for (int c = 0; c < 4; ++c) {
        int idx = i - c;
        if (idx >= 0 && idx < 1344) xh[ch][c][idx] = h;
      }
    }
  }
  __syncthreads();

  int wave = tid >> 6, lane = tid & 63;
  int q = lane >> 4, l16 = lane & 15;
  int band = (l16 >= 10) ? 2 : (l16 >= 5 ? 1 : 0);
  int u = l16 - band * 5;
  if (l16 == 15) { band = 2; u = 4; }          // row 15 = dup of row 14, discarded
  const short* pAh = wt + band * 1152 + 64 + q * 8 - u * 16;
  const short* pAl = pAh + 3456;
  int c = l16 & 3;
  int xoff = wave * 80 + q * 8 + ((l16 >> 2) << 2);
  const short* pB0 = &xh[0][c][xoff];
  const short* pB1 = &xh[1][c][xoff];
  float4v a00 = {0.f,0.f,0.f,0.f}, a01 = {0.f,0.f,0.f,0.f};
  float4v a10 = {0.f,0.f,0.f,0.f}, a11 = {0.f,0.f,0.f,0.f};
#pragma unroll 2
  for (int s = 0; s < 34; ++s) {
    short8v ah = *(const short8v*)(pAh + 32 * s);
    short8v al = *(const short8v*)(pAl + 32 * s);
    short4v b00 = *(const short4v*)(pB0 + 32 * s);
    short4v b01 = *(const short4v*)(pB0 + 32 * s + 4);
    short4v b10 = *(const short4v*)(pB1 + 32 * s);
    short4v b11 = *(const short4v*)(pB1 + 32 * s + 4);
    short8v bh0 = __builtin_shufflevector(b00, b01, 0, 1, 2, 3, 4, 5, 6, 7);
    short8v bh1 = __builtin_shufflevector(b10, b11, 0, 1, 2, 3, 4, 5, 6, 7);
    a00 = __builtin_amdgcn_mfma_f32_16x16x32_bf16(ah, bh0, a00, 0, 0, 0);
    a01 = __builtin_amdgcn_mfma_f32_16x16x32_bf16(al, bh0, a01, 0, 0, 0);
    a10 = __builtin_amdgcn_mfma_f32_16x16x32_bf16(ah, bh1, a10, 0, 0, 0);
    a11 = __builtin_amdgcn_mfma_f32_16x16x32_bf16(al, bh1, a11, 0, 0, 0);
  }
  float acc0[4], acc1[4];
#pragma unroll
  for (int r = 0; r < 4; ++r) { acc0[r] = a00[r] + a01[r]; acc1[r] = a10[r] + a11[r]; }

  float* bands = ws + OFF_BANDS;
#pragma unroll
  for (int r = 0; r < 4; ++r) {
    int m = q * 4 + r;
    if (m < 15) {
      int bnd = (m >= 10) ? 2 : (m >= 5 ? 1 : 0);
      int uu = m - bnd * 5;
      int t = t0b + wave * 80 + uu * 16 + l16;
      if (t < NT) {
        bands[((b * 3 + bnd) * 2 + 0) * NT + t] = acc0[r];
        bands[((b * 3 + bnd) * 2 + 1) * NT + t] = acc1[r];
      }
    }
  }

  // ---- fused RMS partial: sum (y0^2 + y1^2) over each 16-sample group
  float s2[4];
#pragma unroll
  for (int r = 0; r < 4; ++r) {
    int m = q * 4 + r;
    s2[r] = (m < 15) ? acc0[r] * acc0[r] + acc1[r] * acc1[r] : 0.f;
  }
#pragma unroll
  for (int mask = 1; mask < 16; mask <<= 1)
#pragma unroll
    for (int r = 0; r < 4; ++r)
      s2[r] += __shfl_xor(s2[r], mask, 16);
  if (l16 == 0) {
#pragma unroll
    for (int r = 0; r < 4; ++r) {
      int m = q * 4 + r;
      if (m < 15) {
        int bnd = (m >= 10) ? 2 : (m >= 5 ? 1 : 0);
        int uu = m - bnd * 5;
        int jloc = (wave * 80 + uu * 16) >> 6;
        atomicAdd(&ssum[bnd][jloc], s2[r]);
      }
    }
  }
  __syncthreads();
  if (tid < 15) {
    int bnd = tid / 5, jl = tid - bnd * 5;
    int jg = tile * 5 + jl;
    if (jg < TC) atomicAdd(&ws[OFF_XRMS + (b * 3 + bnd) * TC + jg], ssum[bnd][jl]);
  }
}

// ---------------------------------------------------------------- decaying-max scan (+sqrt)
__global__ __launch_bounds__(256) void k_scan(const float* __restrict__ rel_alphas,
                                              float* __restrict__ ws)
{
  __shared__ float sA[TC], sB[TC];
  int row = blockIdx.x;
  int tid = threadIdx.x;
  float kdec = 1.f - rel_alphas[row >> 3];   // reference's repeat() indexing
  const float* xr = ws + OFF_XRMS + row * TC;
  for (int i = tid; i < TC; i += 256)
    sA[i] = sqrtf(xr[i] * (0.5f / 64.f) + 1e-7f);
  __syncthreads();
  float* in = sA; float* outp = sB;
  float kp = kdec;                           // k^off via iterative squaring
  for (int off = 1; off < 2048; off <<= 1) {
    for (int i = tid; i < TC; i += 256) {
      float v = in[i];
      if (i >= off) v = fmaxf(v, in[i - off] * kp);
      outp[i] = v;
    }
    kp *= kp;
    __syncthreads();
    float* tmp = in; in = outp; outp = tmp;
  }
  float* env = ws + OFF_ENV + row * TC;
  for (int i = tid; i < TC; i += 256) env[i] = in[i];
}

// ---------------------------------------------------------------- MFMA conv net (+fused gain)
// R8/R10 geometry: SPAN=128/TILE=96, 512 thr, L1-3 32x32x16 (wave=(ocg,posg)).
// Gain spread over 384 threads into gbuf (union'd with bfL0 — no LDS growth).
// Halo: corruption consumes 1+2+4+8+1=15<16; L4 reads rows 15..112 — clean.
#define PITCH 72
#define SPAN 128
#define TILE 96

__device__ __forceinline__ void mfma_layer32(const short* in, short* outb,
    const short* __restrict__ apk, const float* __restrict__ bias,
    const int d, int t0, int ocg, int posg, int lane)
{
  int l32 = lane & 31, hi = lane >> 5;
  float16v acc;
#pragma unroll
  for (int g = 0; g < 4; ++g) {
    float4 bv = *(const float4*)&bias[ocg * 32 + hi * 4 + g * 8];
    acc[4 * g + 0] = bv.x; acc[4 * g + 1] = bv.y;
    acc[4 * g + 2] = bv.z; acc[4 * g + 3] = bv.w;
  }
  int rbase = posg * 32 + l32;
  int rlo = rbase - d; rlo = rlo < 0 ? 0 : rlo;              // no-op for posg>0
  int rhi = rbase + d; rhi = rhi > SPAN - 1 ? SPAN - 1 : rhi; // no-op for posg<3
  const short* pLo  = in + rlo * PITCH + hi * 8;
  const short* pMid = in + rbase * PITCH + hi * 8;
  const short* pHi  = in + rhi * PITCH + hi * 8;
  const short* ap = apk + (ocg * 12 * 64 + lane) * 8;
#pragma unroll
  for (int s = 0; s < 12; ++s) {
    short8v a = *(const short8v*)(ap + s * 512);
    int tap = s >> 2;
    const short* p = (tap == 0) ? pLo : (tap == 1) ? pMid : pHi;
    short8v bf = *(const short8v*)(p + (s & 3) * 16);
    acc = __builtin_amdgcn_mfma_f32_32x32x16_bf16(a, bf, acc, 0, 0, 0);
  }
  int t = t0 - 16 + rbase;
  bool z = (t < 0) | (t >= NT);
  short* wp = outb + rbase * PITCH + ocg * 32 + hi * 4;
#pragma unroll
  for (int g = 0; g < 4; ++g) {
    short4v r;
#pragma unroll
    for (int q = 0; q < 4; ++q)
      r[q] = f2bft(z ? 0.f : gelus(acc[4 * g + q]));
    *(short4v*)(wp + g * 8) = r;
  }
}

__global__ __launch_bounds__(512, 8) void k_convnet(
    const float* __restrict__ audio, const float* __restrict__ params,
    const float* __restrict__ kneep,
    const float* __restrict__ b0, const float* __restrict__ b1,
    const float* __restrict__ b2, const float* __restrict__ b3,
    const float* __restrict__ b4, const float* __restrict__ ws,
    float* __restrict__ out)
{
  __shared__ float cmb[2][SPAN];
  __shared__ __align__(16) char ubuf[SPAN * 8 * 2];  // union: gbuf (3*SPAN fp32) then bfL0
  __shared__ __align__(16) short actA[SPAN * PITCH];
  __shared__ __align__(16) short actB[SPAN * PITCH];
  float* gbuf = (float*)ubuf;                        // [3][SPAN] = 1536 B <= 2048
  short (*bfL0)[8] = (short(*)[8])ubuf;              // [SPAN][8] = 2048 B
  int tile = blockIdx.x, b = blockIdx.y;
  int t0 = tile * TILE;
  int tid = threadIdx.x;
  int wave = tid >> 6, lane = tid & 63;

  // ---- gain per (band,pos): 384 threads
  if (tid < 3 * SPAN) {
    int band = tid / SPAN, pos = tid - band * SPAN;
    int t = t0 - 16 + pos;
    float g = 0.f;
    if (t >= 0 && t < NT) {
      const float* env = ws + OFF_ENV;
      float knee = kneep[0];
      float halfk = 0.5f * knee;
      float inv2k = 1.f / (2.f * knee);
      const float scale = (float)(1377.0 / 88199.0);
      float pos_f = (float)t * scale;
      int i0 = (int)floorf(pos_f);
      i0 = i0 < 0 ? 0 : (i0 > TC - 2 ? TC - 2 : i0);
      float frac = pos_f - (float)i0;
      const int tacol[3] = {3, 2, 1};
      const int tbcol[3] = {6, 5, 4};
      const float asl[3] = {1.f, (float)(1.0 - 1.0 / 66.7), (float)(1.0 - 1.0 / 66.7)};
      const float bsl = (float)(1.0 - 1.0 / 4.17);
      const float og[3] = {10.3f, 5.7f, 10.3f};
      int row = b * 3 + band;
      float e = env[row * TC + i0] * (1.f - frac) + env[row * TC + i0 + 1] * frac;
      float edb = 6.0205999132796239f * __builtin_amdgcn_logf(e + 1e-7f);  // 20*log10
      float ta = params[b * 7 + tacol[band]];
      float tb = params[b * 7 + tbcol[band]];
      float d1 = edb - ta;
      float gk1 = asl[band] * (d1 + halfk) * (d1 + halfk) * inv2k;
      float ka = (fabsf(d1) <= halfk) ? gk1 : (d1 > halfk ? asl[band] * d1 : 0.f);
      float d2 = tb - edb;
      float gk2 = bsl * (d2 + halfk) * (d2 + halfk) * inv2k;
      float kb = (fabsf(d2) <= halfk) ? gk2 : (d2 > halfk ? bsl * d2 : 0.f);
      float gdb = -ka + kb + og[band];
      gdb = fminf(fmaxf(gdb, -80.f), 40.f);
      g = __builtin_amdgcn_exp2f(gdb * 0.16609640474436812f);   // 10^(gdb/20)
    }
    gbuf[band * SPAN + pos] = g;
  }
  __syncthreads();

  // ---- combine bands -> cmb
  if (tid < SPAN) {
    int t = t0 - 16 + tid;
    float c0 = 0.f, c1 = 0.f;
    if (t >= 0 && t < NT) {
      const float* bands = ws + OFF_BANDS;
#pragma unroll
      for (int band = 0; band < 3; ++band) {
        int row = b * 3 + band;
        float g = gbuf[band * SPAN + tid];
        c0 += bands[(row * 2 + 0) * NT + t] * g;
        c1 += bands[(row * 2 + 1) * NT + t] * g;
      }
    }
    cmb[0][tid] = c0;
    cmb[1][tid] = c1;
  }
  __syncthreads();

  // build bfL0[r][j=k*2+ic] = cmb[ic][r-1+k] (bf16), zero-padded (overwrites gbuf)
  for (int i = tid; i < SPAN * 8; i += 512) {
    int r = i >> 3, j = i & 7;
    short v = 0;
    if (j < 6) {
      int k = j >> 1, ic = j & 1;
      int src = r - 1 + k;
      if (src >= 0 && src < SPAN) v = f2bf(cmb[ic][src]);
    }
    bfL0[r][j] = v;
  }
  __syncthreads();

  int quad = lane >> 4, l16 = lane & 15;

  // ---- L0 (MFMA 16x16x32): single K=32 step (6 live), B=bfL0
  {
    int wq = wave & 3, half = wave >> 2;
    const short* ap0 = (const short*)(ws + OFF_A0);
    short8v a0 = *(const short8v*)&ap0[(wq * 64 + lane) * 8];
    float4 bv = *(const float4*)&b0[wq * 16 + quad * 4];
    float4v acc[4];
#pragma unroll
    for (int n = 0; n < 4; ++n) { acc[n][0] = bv.x; acc[n][1] = bv.y; acc[n][2] = bv.z; acc[n][3] = bv.w; }
    short8v zf = {0, 0, 0, 0, 0, 0, 0, 0};
#pragma unroll
    for (int n = 0; n < 4; ++n) {
      int row = (half * 4 + n) * 16 + l16;
      short8v bf = (quad == 0) ? *(const short8v*)&bfL0[row][0] : zf;
      acc[n] = __builtin_amdgcn_mfma_f32_16x16x32_bf16(a0, bf, acc[n], 0, 0, 0);
    }
    int ocb = wq * 16 + quad * 4;
#pragma unroll
    for (int n = 0; n < 4; ++n) {
      int p = (half * 4 + n) * 16 + l16;
      int t = t0 - 16 + p;
      bool z = (t < 0) | (t >= NT);
      short4v r;
#pragma unroll
      for (int rg = 0; rg < 4; ++rg)
        r[rg] = f2bft(z ? 0.f : gelus(acc[n][rg]));
      *(short4v*)&actA[p * PITCH + ocb] = r;
    }
  }
  __syncthreads();

  int ocg = wave & 1, posg = wave >> 1;
  const short* apk = (const short*)(ws + OFF_ABF);
  mfma_layer32(actA, actB, apk,          b1, 2, t0, ocg, posg, lane);
  __syncthreads();
  mfma_layer32(actB, actA, apk + 12288,  b2, 4, t0, ocg, posg, lane);
  __syncthreads();
  mfma_layer32(actA, actB, apk + 24576,  b3, 8, t0, ocg, posg, lane);
  __syncthreads();

  // ---- L4 (MFMA 16x16x32): rows m=ch (2 live), waves 0..5 cover 96 outputs; + final mix
  if (wave < 6) {
    const short* ap4 = (const short*)(ws + OFF_A4);
    float4v acc = {0.f, 0.f, 0.f, 0.f};
    if (quad == 0) { acc[0] = b4[0]; acc[1] = b4[1]; }
#pragma unroll
    for (int s = 0; s < 6; ++s) {
      short8v a4 = *(const short8v*)&ap4[(s * 64 + lane) * 8];
      int kt = s >> 1;
      int ic0 = (s & 1) * 32 + quad * 8;
      int row = 16 + wave * 16 + l16 + kt - 1;
      short8v bf = *(const short8v*)&actB[row * PITCH + ic0];
      acc = __builtin_amdgcn_mfma_f32_16x16x32_bf16(a4, bf, acc, 0, 0, 0);
    }
    if (quad == 0) {
      int t = t0 + wave * 16 + l16;
      if (t < NT) {
        float amt = params[b * 7];
#pragma unroll
        for (int r = 0; r < 2; ++r) {
          float aud = audio[(b * 2 + r) * NT + t];
          out[(b * 2 + r) * NT + t] =
              (1.f - amt) * aud + amt * (cmb[r][16 + wave * 16 + l16] + acc[r]);
        }
      }
    }
  }
}

// ----------------------------------------------------------------
extern "C" void kernel_launch(void* const* d_in, const int* in_sizes, int n_in,
                              void* d_out, int out_size, void* d_ws, size_t ws_size,
                              hipStream_t stream)
{
  (void)in_sizes; (void)n_in; (void)out_size; (void)ws_size;
  const float* audio = (const float*)d_in[0];
  const float* params = (const float*)d_in[1];
  const float* rel   = (const float*)d_in[2];
  const float* knee  = (const float*)d_in[3];
  const float* irLL  = (const float*)d_in[4];
  const float* irLH  = (const float*)d_in[5];
  const float* irHL  = (const float*)d_in[6];
  const float* irHH  = (const float*)d_in[7];
  const float* w0 = (const float*)d_in[8];  const float* b0 = (const float*)d_in[9];
  const float* w1 = (const float*)d_in[10]; const float* b1 = (const float*)d_in[11];
  const float* w2 = (const float*)d_in[12]; const float* b2 = (const float*)d_in[13];
  const float* w3 = (const float*)d_in[14]; const float* b3 = (const float*)d_in[15];
  const float* w4 = (const float*)d_in[16]; const float* b4 = (const float*)d_in[17];
  float* out = (float*)d_out;
  float* ws  = (float*)d_ws;

  hipLaunchKernelGGL(k_prep, dim3(48, 7), dim3(256), 0, stream,
                     irLL, irLH, irHL, irHH, w0, w1, w2, w3, w4, ws);
  hipLaunchKernelGGL(k_firm, dim3(8, 276), dim3(256), 0, stream, audio, ws);
  hipLaunchKernelGGL(k_scan, dim3(24), dim3(256), 0, stream, rel, ws);
  hipLaunchKernelGGL(k_convnet, dim3(919, 8), dim3(512), 0, stream,
                     audio, params, knee, b0, b1, b2, b3, b4, ws, out);
}

// Round 12
// 299.221 us; speedup vs baseline: 1.0607x; 1.0607x over previous
//
#include <hip/hip_runtime.h>
#include <math.h>

#define NT 88200        // T
#define NB 8            // batch
#define TC 1378         // T // 64

static constexpr float IN_GAIN_F = 1.8197008586099834f; // 10^(5.2/20)

// ---- workspace layout (float offsets) ----
#define OFF_A0    3072         // L0 MFMA A-pack bf16 (2048 shorts)
#define OFF_A4    4096         // L4 MFMA A-pack bf16 (3072 shorts)
#define OFF_ABF   5632         // MFMA A-frag packs (32x32x16 layout), 3 layers x 12288 shorts
#define OFF_BANDS 24064        // [B][3][C][T] = 4233600
#define OFF_XRMS  4257664      // [24][TC] — sum of squares (zeroed by k_prep, atomically acc by k_firm)
#define OFF_ENV   4290736      // [24][TC]
#define OFF_WHL   4290736      // bf16 hi/lo shifted tap tables (9216 shorts) — overlaps ENV:
                               //   written by k_prep, read by k_firm, dead before k_scan writes ENV
// end 4323808 floats ~= 17.3 MB

typedef __attribute__((ext_vector_type(8))) short short8v;
typedef __attribute__((ext_vector_type(4))) short short4v;
typedef __attribute__((ext_vector_type(4))) float float4v;
typedef __attribute__((ext_vector_type(16))) float float16v;

// sigmoid-gelu: x*sigmoid(1.702x); |err| <= 0.021, reaches output only via res (~0.01 scale)
__device__ __forceinline__ float gelus(float x) {
  float e = __builtin_amdgcn_exp2f(-2.4554670f * x);
  return x * __builtin_amdgcn_rcpf(1.f + e);
}
__device__ __forceinline__ short f2bf(float x) {        // RNE
  unsigned int u = __float_as_uint(x);
  u += 0x7fffu + ((u >> 16) & 1u);
  return (short)(u >> 16);
}
__device__ __forceinline__ short f2bft(float x) {       // truncate
  return (short)(__float_as_uint(x) >> 16);
}
__device__ __forceinline__ float bf2f(short s) {
  return __uint_as_float(((unsigned int)(unsigned short)s) << 16);
}

// ---------------------------------------------------------------- prep
// task 0: composite FIR taps -> bf16 hi/lo shifted tables (WHL) incl. zero edges;
// task 1: L0 A-pack; task 2: L4 A-pack; tasks 3..5: 32x32x16 A-packs w1..w3;
// task 6: zero XRMS accumulator.
__global__ __launch_bounds__(256) void k_prep(
    const float* __restrict__ irLL, const float* __restrict__ irLH,
    const float* __restrict__ irHL, const float* __restrict__ irHH,
    const float* __restrict__ w0, const float* __restrict__ w1,
    const float* __restrict__ w2, const float* __restrict__ w3,
    const float* __restrict__ w4, float* __restrict__ ws)
{
  int gid = blockIdx.x * 256 + threadIdx.x;
  int task = blockIdx.y;
  if (task == 0) {
    short* whl = (short*)(ws + OFF_WHL);
    if (gid < 3072) {                       // live taps
      int band = gid >> 10, j = gid & 1023;
      float v = 0.f;
      if (j < 1023) {
        if (band == 2) {                    // low: 512-tap, right-aligned
          v = (j >= 511) ? irLL[j - 511] : 0.f;
        } else {                            // high/mid: conv(irLH, irH?)
          const float* wb = (band == 0) ? irHH : irHL;
          int lo = j - 511; if (lo < 0) lo = 0;
          int hi = (j < 511) ? j : 511;
          float acc = 0.f;
          for (int i = lo; i <= hi; ++i) acc += irLH[i] * wb[j - i];
          v = acc;
        }
      }
      int entry = band * 1152 + 64 + j;
      short h = f2bf(v);
      whl[entry] = h;
      whl[entry + 4608] = f2bf(v - bf2f(h));
    } else if (gid < 4608) {                // zero edges + band 3
      int z = gid - 3072;
      int entry;
      if (z < 384) {
        int band = z >> 7, r = z & 127;
        entry = band * 1152 + (r < 64 ? r : 1024 + r);
      } else {
        entry = 3 * 1152 + (z - 384);
      }
      whl[entry] = 0;
      whl[entry + 4608] = 0;
    }
  } else if (task == 1) {                   // L0 A-pack: m=oc(16/group), K=k*2+ic (6 live)
    if (gid >= 2048) return;
    int wq = gid >> 9;
    int lane = (gid >> 3) & 63;
    int j = gid & 7;
    int l16 = lane & 15, q = lane >> 4;
    int m = wq * 16 + l16;
    int K = q * 8 + j;
    float val = (K < 6) ? w0[(m * 2 + (K & 1)) * 3 + (K >> 1)] : 0.f;
    ((short*)(ws + OFF_A0))[gid] = f2bf(val);
  } else if (task == 2) {                   // L4 A-pack: rows m=ch (2 live of 16)
    if (gid >= 3072) return;
    int s = gid >> 9;
    int lane = (gid - s * 512) >> 3;
    int j = gid & 7;
    int m = lane & 15, q = lane >> 4;
    int K = s * 32 + q * 8 + j;
    int k = K >> 6, ic = K & 63;
    float val = (m < 2) ? w4[(m * 64 + ic) * 3 + k] : 0.f;
    ((short*)(ws + OFF_A4))[gid] = f2bf(val);
  } else if (task == 6) {                   // zero XRMS (24*TC = 33072 floats)
    for (int r = 0; r < 3; ++r) {
      int i = gid * 3 + r;
      if (i < 24 * TC) ws[OFF_XRMS + i] = 0.f;
    }
  } else {                                  // 32x32x16 A-pack layer l (w1..w3)
    int l = task - 3;
    if (gid >= 12288) return;
    const float* wl = (l == 0) ? w1 : (l == 1) ? w2 : w3;
    int ocg = gid / 6144;
    int rem = gid - ocg * 6144;
    int s = rem / 512;
    int rem2 = rem - s * 512;
    int lane = rem2 >> 3;
    int j = gid & 7;
    int m = ocg * 32 + (lane & 31);
    int k = s * 16 + ((lane >> 5) << 3) + j;
    int tap = k >> 6, ic = k & 63;
    short* ap = (short*)(ws + OFF_ABF);
    ap[l * 12288 + gid] = f2bf(wl[(m * 64 + ic) * 3 + tap]);
  }
}

// ---------------------------------------------------------------- MFMA band FIR (+fused RMS partial)
// R10 form (best measured): per-channel blocks, 2-chain hi/lo split.
#define FT 320
__global__ __launch_bounds__(256) void k_firm(const float* __restrict__ audio,
                                              float* __restrict__ ws)
{
  __shared__ short xh[4][1360];
  __shared__ __align__(16) short wt[9216];
  __shared__ float ssum[3][5];
  int bc = blockIdx.x, tile = blockIdx.y;
  int t0b = tile * FT;
  int tid = threadIdx.x;
  if (tid < 15) ssum[tid / 5][tid % 5] = 0.f;
  const uint4* wsrc = (const uint4*)((const short*)(ws + OFF_WHL));
  uint4* wdst = (uint4*)wt;
  for (int i = tid; i < 1152; i += 256) wdst[i] = wsrc[i];   // 9216 shorts = 1152 uint4
  const float* x = audio + bc * NT;
  for (int i = tid; i < 1363; i += 256) {      // unique samples, convert once
    int g = t0b - 1022 + i;
    float v = (g >= 0 && g < NT) ? x[g] * IN_GAIN_F : 0.f;
    short h = f2bf(v);
#pragma unroll
    for (int c = 0; c < 4; ++c) {
      int idx = i - c;
      if (idx >= 0 && idx < 1360) xh[c][idx] = h;
    }
  }
  __syncthreads();

  int wave = tid >> 6, lane = tid & 63;
  int q = lane >> 4, l16 = lane & 15;
  int band = (l16 >= 10) ? 2 : (l16 >= 5 ? 1 : 0);
  if (l16 == 15) band = 3;
  int u = l16 - band * 5;                       // band3 -> u=0 (zero taps)
  const short* pAh = wt + band * 1152 + 64 + q * 8 - u * 16;
  const short* pAl = pAh + 4608;
  int c = l16 & 3;
  int xoff = wave * 80 + q * 8 + ((l16 >> 2) << 2);
  const short* pBh = &xh[c][xoff];
  float4v a0 = {0.f, 0.f, 0.f, 0.f};
  float4v a1 = {0.f, 0.f, 0.f, 0.f};
#pragma unroll 2
  for (int s = 0; s < 34; ++s) {
    short8v ah = *(const short8v*)(pAh + 32 * s);
    short8v al = *(const short8v*)(pAl + 32 * s);
    short4v bh0 = *(const short4v*)(pBh + 32 * s);
    short4v bh1 = *(const short4v*)(pBh + 32 * s + 4);
    short8v bh = __builtin_shufflevector(bh0, bh1, 0, 1, 2, 3, 4, 5, 6, 7);
    a0 = __builtin_amdgcn_mfma_f32_16x16x32_bf16(ah, bh, a0, 0, 0, 0);
    a1 = __builtin_amdgcn_mfma_f32_16x16x32_bf16(al, bh, a1, 0, 0, 0);
  }
  float acc[4];
#pragma unroll
  for (int r = 0; r < 4; ++r) acc[r] = a0[r] + a1[r];

  int b = bc >> 1, ch = bc & 1;
  float* bands = ws + OFF_BANDS;
#pragma unroll
  for (int r = 0; r < 4; ++r) {
    int m = q * 4 + r;
    if (m < 15) {
      int bnd = (m >= 10) ? 2 : (m >= 5 ? 1 : 0);
      int uu = m - bnd * 5;
      int t = t0b + wave * 80 + uu * 16 + l16;
      if (t < NT) bands[((b * 3 + bnd) * 2 + ch) * NT + t] = acc[r];
    }
  }

  // ---- fused RMS partial: sum y^2 over each 16-sample group, accumulate
  float s2[4];
#pragma unroll
  for (int r = 0; r < 4; ++r) {
    int m = q * 4 + r;
    s2[r] = (m < 15) ? acc[r] * acc[r] : 0.f;
  }
#pragma unroll
  for (int mask = 1; mask < 16; mask <<= 1)
#pragma unroll
    for (int r = 0; r < 4; ++r)
      s2[r] += __shfl_xor(s2[r], mask, 16);
  if (l16 == 0) {
#pragma unroll
    for (int r = 0; r < 4; ++r) {
      int m = q * 4 + r;
      if (m < 15) {
        int bnd = (m >= 10) ? 2 : (m >= 5 ? 1 : 0);
        int uu = m - bnd * 5;
        int jloc = (wave * 80 + uu * 16) >> 6;
        atomicAdd(&ssum[bnd][jloc], s2[r]);
      }
    }
  }
  __syncthreads();
  if (tid < 15) {
    int bnd = tid / 5, jl = tid - bnd * 5;
    int jg = tile * 5 + jl;
    if (jg < TC) atomicAdd(&ws[OFF_XRMS + (b * 3 + bnd) * TC + jg], ssum[bnd][jl]);
  }
}

// ---------------------------------------------------------------- decaying-max scan (+sqrt)
// Work-efficient: 6 elems/thread in registers, one 256-wide Hillis-Steele over
// thread-partials (factor k^(6*off)), then register replay with exclusive carry.
__global__ __launch_bounds__(256) void k_scan(const float* __restrict__ rel_alphas,
                                              float* __restrict__ ws)
{
  __shared__ float pA[256], pB[256];
  int row = blockIdx.x;
  int tid = threadIdx.x;
  float kdec = 1.f - rel_alphas[row >> 3];   // reference's repeat() indexing
  const float* xr = ws + OFF_XRMS + row * TC;
  float v[6];
  int base = tid * 6;
#pragma unroll
  for (int s = 0; s < 6; ++s) {
    int j = base + s;
    v[s] = (j < TC) ? sqrtf(xr[j] * (0.5f / 64.f) + 1e-7f) : 0.f;  // pad 0: never wins
  }
  float r = v[0];
#pragma unroll
  for (int s = 1; s < 6; ++s) r = fmaxf(v[s], r * kdec);
  pA[tid] = r;
  __syncthreads();
  float k2 = kdec * kdec, k3 = k2 * kdec;
  float kp = k3 * k3;                        // k^6, then k^(6*off) via squaring
  float* in = pA; float* outp = pB;
  for (int off = 1; off < 256; off <<= 1) {
    float val = in[tid];
    if (tid >= off) val = fmaxf(val, in[tid - off] * kp);
    outp[tid] = val;
    kp *= kp;
    __syncthreads();
    float* tmp = in; in = outp; outp = tmp;
  }
  float* env = ws + OFF_ENV + row * TC;
  float rr;
  if (tid > 0) {
    float carry = in[tid - 1];               // inclusive up to position base-1
    rr = fmaxf(v[0], carry * kdec);
  } else {
    rr = v[0];
  }
  if (base < TC) env[base] = rr;
#pragma unroll
  for (int s = 1; s < 6; ++s) {
    rr = fmaxf(v[s], rr * kdec);
    if (base + s < TC) env[base + s] = rr;
  }
}

// ---------------------------------------------------------------- MFMA conv net (+fused gain)
// R8/R10 geometry: SPAN=128/TILE=96, 512 thr, L1-3 32x32x16 (wave=(ocg,posg)).
// Gain spread over 384 threads into gbuf (union'd with bfL0 — no LDS growth).
// Halo: corruption consumes 1+2+4+8+1=15<16; L4 reads rows 15..112 — clean.
#define PITCH 72
#define SPAN 128
#define TILE 96

__device__ __forceinline__ void mfma_layer32(const short* in, short* outb,
    const short* __restrict__ apk, const float* __restrict__ bias,
    const int d, int t0, int ocg, int posg, int lane)
{
  int l32 = lane & 31, hi = lane >> 5;
  float16v acc;
#pragma unroll
  for (int g = 0; g < 4; ++g) {
    float4 bv = *(const float4*)&bias[ocg * 32 + hi * 4 + g * 8];
    acc[4 * g + 0] = bv.x; acc[4 * g + 1] = bv.y;
    acc[4 * g + 2] = bv.z; acc[4 * g + 3] = bv.w;
  }
  int rbase = posg * 32 + l32;
  int rlo = rbase - d; rlo = rlo < 0 ? 0 : rlo;              // no-op for posg>0
  int rhi = rbase + d; rhi = rhi > SPAN - 1 ? SPAN - 1 : rhi; // no-op for posg<3
  const short* pLo  = in + rlo * PITCH + hi * 8;
  const short* pMid = in + rbase * PITCH + hi * 8;
  const short* pHi  = in + rhi * PITCH + hi * 8;
  const short* ap = apk + (ocg * 12 * 64 + lane) * 8;
#pragma unroll
  for (int s = 0; s < 12; ++s) {
    short8v a = *(const short8v*)(ap + s * 512);
    int tap = s >> 2;
    const short* p = (tap == 0) ? pLo : (tap == 1) ? pMid : pHi;
    short8v bf = *(const short8v*)(p + (s & 3) * 16);
    acc = __builtin_amdgcn_mfma_f32_32x32x16_bf16(a, bf, acc, 0, 0, 0);
  }
  int t = t0 - 16 + rbase;
  bool z = (t < 0) | (t >= NT);
  short* wp = outb + rbase * PITCH + ocg * 32 + hi * 4;
#pragma unroll
  for (int g = 0; g < 4; ++g) {
    short4v r;
#pragma unroll
    for (int q = 0; q < 4; ++q)
      r[q] = f2bft(z ? 0.f : gelus(acc[4 * g + q]));
    *(short4v*)(wp + g * 8) = r;
  }
}

__global__ __launch_bounds__(512, 8) void k_convnet(
    const float* __restrict__ audio, const float* __restrict__ params,
    const float* __restrict__ kneep,
    const float* __restrict__ b0, const float* __restrict__ b1,
    const float* __restrict__ b2, const float* __restrict__ b3,
    const float* __restrict__ b4, const float* __restrict__ ws,
    float* __restrict__ out)
{
  __shared__ float cmb[2][SPAN];
  __shared__ __align__(16) char ubuf[SPAN * 8 * 2];  // union: gbuf (3*SPAN fp32) then bfL0
  __shared__ __align__(16) short actA[SPAN * PITCH];
  __shared__ __align__(16) short actB[SPAN * PITCH];
  float* gbuf = (float*)ubuf;                        // [3][SPAN] = 1536 B <= 2048
  short (*bfL0)[8] = (short(*)[8])ubuf;              // [SPAN][8] = 2048 B
  int tile = blockIdx.x, b = blockIdx.y;
  int t0 = tile * TILE;
  int tid = threadIdx.x;
  int wave = tid >> 6, lane = tid & 63;

  // ---- gain per (band,pos): 384 threads
  if (tid < 3 * SPAN) {
    int band = tid / SPAN, pos = tid - band * SPAN;
    int t = t0 - 16 + pos;
    float g = 0.f;
    if (t >= 0 && t < NT) {
      const float* env = ws + OFF_ENV;
      float knee = kneep[0];
      float halfk = 0.5f * knee;
      float inv2k = 1.f / (2.f * knee);
      const float scale = (float)(1377.0 / 88199.0);
      float pos_f = (float)t * scale;
      int i0 = (int)floorf(pos_f);
      i0 = i0 < 0 ? 0 : (i0 > TC - 2 ? TC - 2 : i0);
      float frac = pos_f - (float)i0;
      const int tacol[3] = {3, 2, 1};
      const int tbcol[3] = {6, 5, 4};
      const float asl[3] = {1.f, (float)(1.0 - 1.0 / 66.7), (float)(1.0 - 1.0 / 66.7)};
      const float bsl = (float)(1.0 - 1.0 / 4.17);
      const float og[3] = {10.3f, 5.7f, 10.3f};
      int row = b * 3 + band;
      float e = env[row * TC + i0] * (1.f - frac) + env[row * TC + i0 + 1] * frac;
      float edb = 6.0205999132796239f * __builtin_amdgcn_logf(e + 1e-7f);  // 20*log10
      float ta = params[b * 7 + tacol[band]];
      float tb = params[b * 7 + tbcol[band]];
      float d1 = edb - ta;
      float gk1 = asl[band] * (d1 + halfk) * (d1 + halfk) * inv2k;
      float ka = (fabsf(d1) <= halfk) ? gk1 : (d1 > halfk ? asl[band] * d1 : 0.f);
      float d2 = tb - edb;
      float gk2 = bsl * (d2 + halfk) * (d2 + halfk) * inv2k;
      float kb = (fabsf(d2) <= halfk) ? gk2 : (d2 > halfk ? bsl * d2 : 0.f);
      float gdb = -ka + kb + og[band];
      gdb = fminf(fmaxf(gdb, -80.f), 40.f);
      g = __builtin_amdgcn_exp2f(gdb * 0.16609640474436812f);   // 10^(gdb/20)
    }
    gbuf[band * SPAN + pos] = g;
  }
  __syncthreads();

  // ---- combine bands -> cmb
  if (tid < SPAN) {
    int t = t0 - 16 + tid;
    float c0 = 0.f, c1 = 0.f;
    if (t >= 0 && t < NT) {
      const float* bands = ws + OFF_BANDS;
#pragma unroll
      for (int band = 0; band < 3; ++band) {
        int row = b * 3 + band;
        float g = gbuf[band * SPAN + tid];
        c0 += bands[(row * 2 + 0) * NT + t] * g;
        c1 += bands[(row * 2 + 1) * NT + t] * g;
      }
    }
    cmb[0][tid] = c0;
    cmb[1][tid] = c1;
  }
  __syncthreads();

  // build bfL0[r][j=k*2+ic] = cmb[ic][r-1+k] (bf16), zero-padded (overwrites gbuf)
  for (int i = tid; i < SPAN * 8; i += 512) {
    int r = i >> 3, j = i & 7;
    short v = 0;
    if (j < 6) {
      int k = j >> 1, ic = j & 1;
      int src = r - 1 + k;
      if (src >= 0 && src < SPAN) v = f2bf(cmb[ic][src]);
    }
    bfL0[r][j] = v;
  }
  __syncthreads();

  int quad = lane >> 4, l16 = lane & 15;

  // ---- L0 (MFMA 16x16x32): single K=32 step (6 live), B=bfL0
  {
    int wq = wave & 3, half = wave >> 2;
    const short* ap0 = (const short*)(ws + OFF_A0);
    short8v a0 = *(const short8v*)&ap0[(wq * 64 + lane) * 8];
    float4 bv = *(const float4*)&b0[wq * 16 + quad * 4];
    float4v acc[4];
#pragma unroll
    for (int n = 0; n < 4; ++n) { acc[n][0] = bv.x; acc[n][1] = bv.y; acc[n][2] = bv.z; acc[n][3] = bv.w; }
    short8v zf = {0, 0, 0, 0, 0, 0, 0, 0};
#pragma unroll
    for (int n = 0; n < 4; ++n) {
      int row = (half * 4 + n) * 16 + l16;
      short8v bf = (quad == 0) ? *(const short8v*)&bfL0[row][0] : zf;
      acc[n] = __builtin_amdgcn_mfma_f32_16x16x32_bf16(a0, bf, acc[n], 0, 0, 0);
    }
    int ocb = wq * 16 + quad * 4;
#pragma unroll
    for (int n = 0; n < 4; ++n) {
      int p = (half * 4 + n) * 16 + l16;
      int t = t0 - 16 + p;
      bool z = (t < 0) | (t >= NT);
      short4v r;
#pragma unroll
      for (int rg = 0; rg < 4; ++rg)
        r[rg] = f2bft(z ? 0.f : gelus(acc[n][rg]));
      *(short4v*)&actA[p * PITCH + ocb] = r;
    }
  }
  __syncthreads();

  int ocg = wave & 1, posg = wave >> 1;
  const short* apk = (const short*)(ws + OFF_ABF);
  mfma_layer32(actA, actB, apk,          b1, 2, t0, ocg, posg, lane);
  __syncthreads();
  mfma_layer32(actB, actA, apk + 12288,  b2, 4, t0, ocg, posg, lane);
  __syncthreads();
  mfma_layer32(actA, actB, apk + 24576,  b3, 8, t0, ocg, posg, lane);
  __syncthreads();

  // ---- L4 (MFMA 16x16x32): rows m=ch (2 live), waves 0..5 cover 96 outputs; + final mix
  if (wave < 6) {
    const short* ap4 = (const short*)(ws + OFF_A4);
    float4v acc = {0.f, 0.f, 0.f, 0.f};
    if (quad == 0) { acc[0] = b4[0]; acc[1] = b4[1]; }
#pragma unroll
    for (int s = 0; s < 6; ++s) {
      short8v a4 = *(const short8v*)&ap4[(s * 64 + lane) * 8];
      int kt = s >> 1;
      int ic0 = (s & 1) * 32 + quad * 8;
      int row = 16 + wave * 16 + l16 + kt - 1;
      short8v bf = *(const short8v*)&actB[row * PITCH + ic0];
      acc = __builtin_amdgcn_mfma_f32_16x16x32_bf16(a4, bf, acc, 0, 0, 0);
    }
    if (quad == 0) {
      int t = t0 + wave * 16 + l16;
      if (t < NT) {
        float amt = params[b * 7];
#pragma unroll
        for (int r = 0; r < 2; ++r) {
          float aud = audio[(b * 2 + r) * NT + t];
          out[(b * 2 + r) * NT + t] =
              (1.f - amt) * aud + amt * (cmb[r][16 + wave * 16 + l16] + acc[r]);
        }
      }
    }
  }
}

// ----------------------------------------------------------------
extern "C" void kernel_launch(void* const* d_in, const int* in_sizes, int n_in,
                              void* d_out, int out_size, void* d_ws, size_t ws_size,
                              hipStream_t stream)
{
  (void)in_sizes; (void)n_in; (void)out_size; (void)ws_size;
  const float* audio = (const float*)d_in[0];
  const float* params = (const float*)d_in[1];
  const float* rel   = (const float*)d_in[2];
  const float* knee  = (const float*)d_in[3];
  const float* irLL  = (const float*)d_in[4];
  const float* irLH  = (const float*)d_in[5];
  const float* irHL  = (const float*)d_in[6];
  const float* irHH  = (const float*)d_in[7];
  const float* w0 = (const float*)d_in[8];  const float* b0 = (const float*)d_in[9];
  const float* w1 = (const float*)d_in[10]; const float* b1 = (const float*)d_in[11];
  const float* w2 = (const float*)d_in[12]; const float* b2 = (const float*)d_in[13];
  const float* w3 = (const float*)d_in[14]; const float* b3 = (const float*)d_in[15];
  const float* w4 = (const float*)d_in[16]; const float* b4 = (const float*)d_in[17];
  float* out = (float*)d_out;
  float* ws  = (float*)d_ws;

  hipLaunchKernelGGL(k_prep, dim3(48, 7), dim3(256), 0, stream,
                     irLL, irLH, irHL, irHH, w0, w1, w2, w3, w4, ws);
  hipLaunchKernelGGL(k_firm, dim3(16, 276), dim3(256), 0, stream, audio, ws);
  hipLaunchKernelGGL(k_scan, dim3(24), dim3(256), 0, stream, rel, ws);
  hipLaunchKernelGGL(k_convnet, dim3(919, 8), dim3(512), 0, stream,
                     audio, params, knee, b0, b1, b2, b3, b4, ws, out);
}